// Round 4
// baseline (6367.965 us; speedup 1.0000x reference)
//
#include <hip/hip_runtime.h>
#include <hip/hip_bf16.h>

// GRU-imputation scan (B=128,T=128,D=128,H=1024,L=3), f32 in/out.
// Round 8: re-partition 4x32 -> 8x16. 8 row-groups of 16 rows, 16 blocks per
// group (each owns 64 h-cols). Halves the redundant coherent stage traffic
// (FETCH ~4.3GB -> ~2.2GB), which R5-R7 indicate is the binding constraint
// (dur ~= FETCH / 800GB/s in all three). M=16 rows = one MFMA tile: each wave
// does full-K (no K-split reduce). 3 phases/step, IC fused in L0 (as R6/R7).

typedef __hip_bfloat16 bf16;
typedef unsigned int u32;
typedef unsigned short u16;
typedef __attribute__((ext_vector_type(8))) short v8bf;   // 8 x bf16 (16B)
typedef __attribute__((ext_vector_type(4))) float v4f;    // MFMA C/D
typedef __attribute__((ext_vector_type(4))) u32 v4u;

#define SC __HIP_MEMORY_SCOPE_AGENT

__device__ __forceinline__ float bf2f(bf16 v){ return __bfloat162float(v); }
__device__ __forceinline__ bf16 f2bf(float v){ return __float2bfloat16(v); }
__device__ __forceinline__ float sigm(float x){ return 1.f/(1.f + __expf(-x)); }
__device__ __forceinline__ float tanh_(float x){
  float a = fminf(fmaxf(x, -15.f), 15.f);
  float t = __expf(2.f*a);
  return (t-1.f)/(t+1.f);
}
__device__ __forceinline__ v8bf ldv(const bf16* p){ return *reinterpret_cast<const v8bf*>(p); }
__device__ __forceinline__ void vdrain(){ asm volatile("s_waitcnt vmcnt(0)" ::: "memory"); }

// ---- device-coherent (LLC) accesses: bypass L1+L2 via sc0 sc1 ----
__device__ __forceinline__ void ldx2_coh(const bf16* p0, const bf16* p1,
                                         v4u& r0, v4u& r1){
  asm volatile(
    "global_load_dwordx4 %0, %2, off sc0 sc1\n\t"
    "global_load_dwordx4 %1, %3, off sc0 sc1\n\t"
    "s_waitcnt vmcnt(0)"
    : "=&v"(r0), "=&v"(r1)
    : "v"(p0), "v"(p1)
    : "memory");
}
__device__ __forceinline__ void st2_coh(bf16* p, bf16 v){
  u32 vv = (u32)__builtin_bit_cast(u16, v);
  asm volatile("global_store_short %0, %1, off sc0 sc1" :: "v"(p), "v"(vv) : "memory");
}

// ---- flag-array barrier: 16 slots/group, monotonic epochs, no RMW ----
__device__ __forceinline__ void gbar(u32* slots, int slot, u32 target, int lane){
  __syncthreads();
  if (threadIdx.x < 64){
    if (lane == 0){
      vdrain();                                     // my coherent stores at LLC
      __hip_atomic_store(slots + slot, target, __ATOMIC_RELAXED, SC);
    }
    u32 v = __hip_atomic_load(slots + (lane & 15), __ATOMIC_RELAXED, SC);
    while (!__all(v >= target)){
      __builtin_amdgcn_s_sleep(1);
      v = __hip_atomic_load(slots + (lane & 15), __ATOMIC_RELAXED, SC);
    }
  }
  __syncthreads();
}

// =================================================================
// Packing kernels (unchanged; validated).
// Fragment unit = 64 lanes x 8 bf16; lane's 8 elems =
//   W[row(j,lane&15)][kk*32 + ((lane>>4)&3)*8 + e]
// =================================================================
__global__ void pack_upper_k(const float* __restrict__ Wih, const float* __restrict__ Whh,
                             bf16* __restrict__ dst){
  int tid = blockIdx.x*256 + threadIdx.x;          // 1,048,576
  int lane = tid & 63;
  int u    = tid >> 6;
  int kk   = u & 31;
  int j    = (u >> 5) & 63;
  int s    = (u >> 11) & 3;
  int l    = u >> 13;
  int n    = j*16 + (lane & 15);
  int k    = kk*32 + ((lane>>4)&3)*8;
  int row  = (s==0) ? n : (s==1 ? 1024+n : 2048+n);
  size_t src = ((size_t)l*3072 + row)*1024 + k;
  size_t o = (size_t)tid*8;
  #pragma unroll
  for (int e=0;e<8;e++){
    float v;
    if (s < 2)      v = Wih[src+e] + Whh[src+e];
    else if (s==2)  v = Wih[src+e];
    else            v = Whh[src+e];
    dst[o+e] = f2bf(v);
  }
}
__global__ void pack_l0h_k(const float* __restrict__ Whh0, bf16* __restrict__ dst){
  int tid = blockIdx.x*256 + threadIdx.x;          // 393,216
  int lane = tid & 63;
  int u  = tid >> 6;
  int kk = u & 31;
  int j  = (u >> 5) & 63;
  int g  = u >> 11;
  int row = g*1024 + j*16 + (lane&15);
  int k   = kk*32 + ((lane>>4)&3)*8;
  size_t src = (size_t)row*1024 + k;
  size_t o = (size_t)tid*8;
  #pragma unroll
  for (int e=0;e<8;e++) dst[o+e] = f2bf(Whh0[src+e]);
}
__global__ void pack_l0x_k(const float* __restrict__ Wih0, bf16* __restrict__ dst){
  int tid = blockIdx.x*256 + threadIdx.x;          // 49,152
  int lane = tid & 63;
  int u  = tid >> 6;
  int kk = u & 3;
  int j  = (u >> 2) & 63;
  int g  = u >> 8;
  int row = g*1024 + j*16 + (lane&15);
  int k   = kk*32 + ((lane>>4)&3)*8;
  size_t src = (size_t)row*128 + k;
  size_t o = (size_t)tid*8;
  #pragma unroll
  for (int e=0;e<8;e++) dst[o+e] = f2bf(Wih0[src+e]);
}
__global__ void pack_imp_k(const float* __restrict__ Wp, bf16* __restrict__ dst){
  int tid = blockIdx.x*256 + threadIdx.x;          // 16,384
  int lane = tid & 63;
  int u  = tid >> 6;
  int kk = u & 31;
  int jj = u >> 5;
  int row = jj*16 + (lane&15);
  int k   = kk*32 + ((lane>>4)&3)*8;
  size_t src = (size_t)row*1024 + k;
  size_t o = (size_t)tid*8;
  #pragma unroll
  for (int e=0;e<8;e++) dst[o+e] = f2bf(Wp[src+e]);
}
__global__ void init_pk(u32* __restrict__ bar, bf16* __restrict__ h3){
  int tid = blockIdx.x*256 + threadIdx.x;          // 393,216
  if (tid < 1024) bar[tid] = 0u;
  h3[tid] = f2bf(0.f);                             // hA, hB, hC = 0
}

// =================================================================
// Staging: 16 rows x 1024 cols of h (row stride 1024) -> fragment-ordered
// LDS (32 KB). unit = kk (0..31); lane's 8 elems =
//   h[lane&15][kk*32 + (lane>>4)*8 + e]. wave w stages kk = 2w, 2w+1.
// =================================================================
__device__ __forceinline__ void stage_h16(const bf16* __restrict__ src_rg, bf16* lds_h,
                                          int wave, int lane, int l15, int quad){
  const bf16* g0 = src_rg + (size_t)l15*1024 + wave*64 + quad*8;
  v4u r0, r1;
  ldx2_coh(g0, g0 + 32, r0, r1);
  bf16* d = lds_h + ((size_t)wave*2)*512 + (size_t)lane*8;
  *(v4u*)(d)       = r0;
  *(v4u*)(d + 512) = r1;
}
// A-fragment from staged LDS: K-chunk kk
__device__ __forceinline__ v8bf afrag(const bf16* lds_h, int kk, int lane){
  return ldv(lds_h + (size_t)kk*512 + (size_t)lane*8);
}
// scalar element (rl, colh) from staged LDS
__device__ __forceinline__ float hp16(const bf16* lds_h, int rl, int colh){
  int kk = colh >> 5, q = (colh >> 3) & 3, e = colh & 7;
  return bf2f(lds_h[(size_t)kk*512 + (size_t)(q*16 + rl)*8 + e]);
}

#define MFMA(a,b,c) __builtin_amdgcn_mfma_f32_16x16x32_bf16((a),(b),(c),0,0,0)

// lds2 tile: 16x16 f32 at stride 17 (pad), tile stride 272
#define T_W(w, row, col)  lds2[(w)*272 + (row)*17 + (col)]

// =================================================================
// Main persistent kernel: 128 blocks x 1024 threads (16 waves).
// bid: cseg = bid&15 (output cols cseg*64..+63; cseg&7 = XCD affinity),
// g = bid>>4 (row group of 16 rows). 16 blocks per group.
// 3 grid-barrier phases per step: L0 (with fused IC for step t-1), L1, L2.
// =================================================================
__global__ __launch_bounds__(1024, 4) void gru_pk(
  const float* __restrict__ x, const float* __restrict__ masks,
  const float* __restrict__ bih0, const float* __restrict__ bhh0,
  const float* __restrict__ bihR, const float* __restrict__ bhhR,
  const float* __restrict__ bp,
  const bf16* __restrict__ packU, const bf16* __restrict__ packL0h,
  const bf16* __restrict__ packL0x, const bf16* __restrict__ packImp,
  bf16* hA, bf16* hB, bf16* hC,
  u32* bar, float* out)
{
  const int tid  = threadIdx.x;
  const int lane = tid & 63;
  const int wave = tid >> 6;           // 0..15
  const int l15  = lane & 15;
  const int quad = lane >> 4;
  const int bid  = blockIdx.x;
  const int cseg = bid & 15;           // col segment (64 cols), low 3 bits = XCD
  const int g    = bid >> 4;           // row group 0..7
  const int rB   = g * 16;             // first row
  u32* slots = bar + g*64;             // 16 flag slots (one line per group)

  __shared__ bf16 lds_h[16384];        // 32 KB staged h slice (16 x 1024)
  __shared__ bf16 lds_c[2048];         // 4 KB staged comp slice (16 x 128)
  __shared__ float lds2[24*272];       // ~25.5 KB partial tiles (padded)
  u32 bc = 0;

  #pragma unroll 1
  for (int t = 0; t < 128; ++t){
    // ====== L0: fused IC(t-1) + hB = GRU0(input=comp(t-1), hidden=hA) ======
    {
      stage_h16(hA + (size_t)rB*1024, lds_h, wave, lane, l15, quad);
      __syncthreads();
      // ---- fused IC: build comp slice into lds_c (and write out for t>=1) ----
      if (t == 0){
        // comp(-1) = x[:, 0, :]; thread (wave=row rl, lane -> d, d+64)
        const int rl = wave;
        #pragma unroll
        for (int half=0; half<2; ++half){
          const int d = lane + half*64;
          float v = x[(size_t)(rB+rl)*16384 + d];
          lds_c[(size_t)(d>>5)*512 + (size_t)(((d>>3)&3)*16 + rl)*8 + (d&7)] = f2bf(v);
        }
      } else {
        // imp(t-1)[16,128] = lds_h @ Wp^T + bp, redundant per block.
        // wave w: d-tile jt=w>>1, K-half kh=w&1 (16 kk each)
        const int jt = wave >> 1, kh = wave & 1;
        v4f acc = {0.f,0.f,0.f,0.f};
        const bf16* wp = packImp + ((size_t)(jt*32 + kh*16))*512 + lane*8;
        #pragma unroll
        for (int i=0;i<16;++i){
          acc = MFMA(afrag(lds_h, kh*16+i, lane), ldv(wp + (size_t)i*512), acc);
        }
        #pragma unroll
        for (int r=0;r<4;r++) T_W(wave, quad*4+r, l15) = acc[r];
        __syncthreads();
        // epilogue: thread (rl=wave, lane -> d, d+64)
        const int rl = wave, tm = t - 1;
        const float m = masks[(size_t)(rB+rl)*128 + tm];
        #pragma unroll
        for (int half=0; half<2; ++half){
          const int d = lane + half*64;
          const int djt = d >> 4, c = d & 15;
          float imp = T_W(djt*2, rl, c) + T_W(djt*2+1, rl, c) + bp[d];
          float xv  = x[((size_t)(rB+rl)*128 + tm)*128 + d];
          float cv  = m*xv + (1.f - m)*imp;
          lds_c[(size_t)(d>>5)*512 + (size_t)(((d>>3)&3)*16 + rl)*8 + (d&7)] = f2bf(cv);
          if ((d >> 3) == cseg){
            size_t o = ((size_t)(rB+rl)*127 + tm)*128 + d;
            out[131072 + o]  = cv;    // completed
            out[2211840 + o] = imp;   // imputed
          }
        }
      }
      __syncthreads();
      // ---- main L0 matmuls ----
      if (wave < 12){
        // h-part: wave = gate*4 + jt, full K=1024 (2 accumulators)
        const int gg = wave >> 2, jt = wave & 3;
        const int j = cseg*4 + jt;
        v4f a0 = {0.f,0.f,0.f,0.f}, a1 = {0.f,0.f,0.f,0.f};
        const bf16* wp = packL0h + ((size_t)((gg*64 + j)*32))*512 + lane*8;
        #pragma unroll
        for (int i=0;i<32;i+=2){
          a0 = MFMA(afrag(lds_h, i,   lane), ldv(wp + (size_t)i*512),     a0);
          a1 = MFMA(afrag(lds_h, i+1, lane), ldv(wp + (size_t)(i+1)*512), a1);
        }
        const v4f a = a0 + a1;
        #pragma unroll
        for (int r=0;r<4;r++) T_W(wave, quad*4+r, l15) = a[r];
      } else {
        // x-part: wave 12+jt handles gates 0..2, K=128
        const int jt = wave - 12;
        const int j = cseg*4 + jt;
        #pragma unroll
        for (int gg=0; gg<3; ++gg){
          v4f a = {0.f,0.f,0.f,0.f};
          const bf16* wp = packL0x + ((size_t)((gg*64 + j)*4))*512 + lane*8;
          #pragma unroll
          for (int i=0;i<4;++i){
            a = MFMA(ldv(lds_c + (size_t)i*512 + lane*8), ldv(wp + (size_t)i*512), a);
          }
          const int slot = 12 + gg*4 + jt;
          #pragma unroll
          for (int r=0;r<4;r++) T_W(slot, quad*4+r, l15) = a[r];
        }
      }
      __syncthreads();
      {
        const int rl = wave, cb = lane;
        const int jt = cb >> 4, c = cb & 15;
        const int col = cseg*64 + cb;
        float ghr = T_W(0*4+jt, rl, c);
        float ghz = T_W(1*4+jt, rl, c);
        float ghn = T_W(2*4+jt, rl, c);
        float gir = T_W(12+0*4+jt, rl, c);
        float giz = T_W(12+1*4+jt, rl, c);
        float gin = T_W(12+2*4+jt, rl, c);
        float rgg = sigm(gir + bih0[col]      + ghr + bhh0[col]);
        float zg  = sigm(giz + bih0[1024+col] + ghz + bhh0[1024+col]);
        float nv  = tanh_(gin + bih0[2048+col] + rgg*(ghn + bhh0[2048+col]));
        float hp  = hp16(lds_h, rl, col);
        st2_coh(hB + (size_t)(rB+rl)*1024 + col, f2bf((1.f - zg)*nv + zg*hp));
        vdrain();
      }
      gbar(slots, cseg, ++bc, lane);
    }

    // ================= L1 / L2: upper layers =================
    #pragma unroll 1
    for (int lay = 0; lay < 2; ++lay){
      const bf16* src = lay ? hC : hB;
      bf16*       dst = lay ? hA : hC;
      const bf16* packL = packU + (size_t)lay*4194304;
      const float* bi = bihR + lay*3072;
      const float* bh = bhhR + lay*3072;
      float* out_h = (lay == 1 && t == 127) ? out : nullptr;

      stage_h16(src + (size_t)rB*1024, lds_h, wave, lane, l15, quad);
      __syncthreads();
      {
        // wave = jt*4 + s; full K=1024 (2 accumulators)
        const int s = wave & 3, jt = wave >> 2;
        const int j = cseg*4 + jt;
        v4f a0 = {0.f,0.f,0.f,0.f}, a1 = {0.f,0.f,0.f,0.f};
        const bf16* wp = packL + ((size_t)((s*64 + j)*32))*512 + lane*8;
        #pragma unroll
        for (int i=0;i<32;i+=2){
          a0 = MFMA(afrag(lds_h, i,   lane), ldv(wp + (size_t)i*512),     a0);
          a1 = MFMA(afrag(lds_h, i+1, lane), ldv(wp + (size_t)(i+1)*512), a1);
        }
        const v4f a = a0 + a1;
        #pragma unroll
        for (int r=0;r<4;r++) T_W(wave, quad*4+r, l15) = a[r];
      }
      __syncthreads();
      {
        const int rl = wave, cb = lane;
        const int jt = cb >> 4, c = cb & 15;
        const int col = cseg*64 + cb;
        float pr  = T_W(jt*4+0, rl, c);
        float pz  = T_W(jt*4+1, rl, c);
        float pin = T_W(jt*4+2, rl, c);
        float phn = T_W(jt*4+3, rl, c);
        float rgg = sigm(pr + bi[col] + bh[col]);
        float zg  = sigm(pz + bi[1024+col] + bh[1024+col]);
        float nv  = tanh_(pin + bi[2048+col] + rgg*(phn + bh[2048+col]));
        float hp  = hp16(lds_h, rl, col);
        float hv  = (1.f - zg)*nv + zg*hp;
        st2_coh(dst + (size_t)(rB+rl)*1024 + col, f2bf(hv));
        if (out_h) out_h[(size_t)(rB+rl)*1024 + col] = hv;
        vdrain();
      }
      gbar(slots, cseg, ++bc, lane);
    }
  }
}

// ---------------- host ----------------
extern "C" void kernel_launch(void* const* d_in, const int* in_sizes, int n_in,
                              void* d_out, int out_size, void* d_ws, size_t ws_size,
                              hipStream_t stream)
{
  (void)in_sizes; (void)n_in; (void)out_size; (void)ws_size;
  const float* x     = (const float*)d_in[0];
  const float* masks = (const float*)d_in[1];
  const float* Wih0  = (const float*)d_in[2];
  const float* Whh0  = (const float*)d_in[3];
  const float* bih0  = (const float*)d_in[4];
  const float* bhh0  = (const float*)d_in[5];
  const float* WihR  = (const float*)d_in[6];
  const float* WhhR  = (const float*)d_in[7];
  const float* bihR  = (const float*)d_in[8];
  const float* bhhR  = (const float*)d_in[9];
  const float* Wp    = (const float*)d_in[10];
  const float* bp    = (const float*)d_in[11];
  float* out = (float*)d_out;

  // ws: bar u32[1024] | hA hB hC (bf16 131072 ea) | packed weights
  u32*  bar     = (u32*)d_ws;
  bf16* hA      = (bf16*)((char*)d_ws + 4096);
  bf16* hB      = hA + 131072;
  bf16* hC      = hB + 131072;
  bf16* packU   = hC + 131072;         // 8,388,608 elems
  bf16* packL0h = packU + 8388608;     // 3,145,728
  bf16* packL0x = packL0h + 3145728;   // 393,216
  bf16* packImp = packL0x + 393216;    // 131,072

  hipLaunchKernelGGL(init_pk,      dim3(1536), dim3(256), 0, stream, bar, hA);
  hipLaunchKernelGGL(pack_upper_k, dim3(4096), dim3(256), 0, stream, WihR, WhhR, packU);
  hipLaunchKernelGGL(pack_l0h_k,   dim3(1536), dim3(256), 0, stream, Whh0, packL0h);
  hipLaunchKernelGGL(pack_l0x_k,   dim3(192),  dim3(256), 0, stream, Wih0, packL0x);
  hipLaunchKernelGGL(pack_imp_k,   dim3(64),   dim3(256), 0, stream, Wp, packImp);
  hipLaunchKernelGGL(gru_pk,       dim3(128),  dim3(1024), 0, stream,
      x, masks, bih0, bhh0, bihR, bhhR, bp,
      packU, packL0h, packL0x, packImp, hA, hB, hC, bar, out);
}

// Round 8
// 3618.163 us; speedup vs baseline: 1.7600x; 1.7600x over previous
//
#include <hip/hip_runtime.h>
#include <hip/hip_bf16.h>

// GRU-imputation scan (B=128,T=128,D=128,H=1024,L=3), f32 in/out.
// Round 10: multi-kernel pipeline. The persistent kernel + software grid
// barriers + coherent sc0/sc1 asm are replaced by 384 small kernels (3 per
// timestep: L0-with-fused-IC, L1, L2) enqueued on the stream. Kernel
// boundaries provide cross-XCD release/acquire, so all memory ops are plain
// cached loads/stores. Compute bodies are ported verbatim from the validated
// R8 kernel (absmax 9.8e-4), with t hoisted to a kernel argument.
// cseg = bid&15 keeps cseg&7 == bid&7 == XCD for weight L2 affinity.

typedef __hip_bfloat16 bf16;
typedef unsigned int u32;
typedef unsigned short u16;
typedef __attribute__((ext_vector_type(8))) short v8bf;   // 8 x bf16 (16B)
typedef __attribute__((ext_vector_type(4))) float v4f;    // MFMA C/D
typedef __attribute__((ext_vector_type(4))) u32 v4u;

__device__ __forceinline__ float bf2f(bf16 v){ return __bfloat162float(v); }
__device__ __forceinline__ bf16 f2bf(float v){ return __float2bfloat16(v); }
__device__ __forceinline__ float sigm(float x){ return 1.f/(1.f + __expf(-x)); }
__device__ __forceinline__ float tanh_(float x){
  float a = fminf(fmaxf(x, -15.f), 15.f);
  float t = __expf(2.f*a);
  return (t-1.f)/(t+1.f);
}
__device__ __forceinline__ v8bf ldv(const bf16* p){ return *reinterpret_cast<const v8bf*>(p); }

// =================================================================
// Packing kernels (unchanged; validated).
// Fragment unit = 64 lanes x 8 bf16; lane's 8 elems =
//   W[row(j,lane&15)][kk*32 + ((lane>>4)&3)*8 + e]
// =================================================================
__global__ void pack_upper_k(const float* __restrict__ Wih, const float* __restrict__ Whh,
                             bf16* __restrict__ dst){
  int tid = blockIdx.x*256 + threadIdx.x;          // 1,048,576
  int lane = tid & 63;
  int u    = tid >> 6;
  int kk   = u & 31;
  int j    = (u >> 5) & 63;
  int s    = (u >> 11) & 3;
  int l    = u >> 13;
  int n    = j*16 + (lane & 15);
  int k    = kk*32 + ((lane>>4)&3)*8;
  int row  = (s==0) ? n : (s==1 ? 1024+n : 2048+n);
  size_t src = ((size_t)l*3072 + row)*1024 + k;
  size_t o = (size_t)tid*8;
  #pragma unroll
  for (int e=0;e<8;e++){
    float v;
    if (s < 2)      v = Wih[src+e] + Whh[src+e];
    else if (s==2)  v = Wih[src+e];
    else            v = Whh[src+e];
    dst[o+e] = f2bf(v);
  }
}
__global__ void pack_l0h_k(const float* __restrict__ Whh0, bf16* __restrict__ dst){
  int tid = blockIdx.x*256 + threadIdx.x;          // 393,216
  int lane = tid & 63;
  int u  = tid >> 6;
  int kk = u & 31;
  int j  = (u >> 5) & 63;
  int g  = u >> 11;
  int row = g*1024 + j*16 + (lane&15);
  int k   = kk*32 + ((lane>>4)&3)*8;
  size_t src = (size_t)row*1024 + k;
  size_t o = (size_t)tid*8;
  #pragma unroll
  for (int e=0;e<8;e++) dst[o+e] = f2bf(Whh0[src+e]);
}
__global__ void pack_l0x_k(const float* __restrict__ Wih0, bf16* __restrict__ dst){
  int tid = blockIdx.x*256 + threadIdx.x;          // 49,152
  int lane = tid & 63;
  int u  = tid >> 6;
  int kk = u & 3;
  int j  = (u >> 2) & 63;
  int g  = u >> 8;
  int row = g*1024 + j*16 + (lane&15);
  int k   = kk*32 + ((lane>>4)&3)*8;
  size_t src = (size_t)row*128 + k;
  size_t o = (size_t)tid*8;
  #pragma unroll
  for (int e=0;e<8;e++) dst[o+e] = f2bf(Wih0[src+e]);
}
__global__ void pack_imp_k(const float* __restrict__ Wp, bf16* __restrict__ dst){
  int tid = blockIdx.x*256 + threadIdx.x;          // 16,384
  int lane = tid & 63;
  int u  = tid >> 6;
  int kk = u & 31;
  int jj = u >> 5;
  int row = jj*16 + (lane&15);
  int k   = kk*32 + ((lane>>4)&3)*8;
  size_t src = (size_t)row*1024 + k;
  size_t o = (size_t)tid*8;
  #pragma unroll
  for (int e=0;e<8;e++) dst[o+e] = f2bf(Wp[src+e]);
}
__global__ void init_pk(bf16* __restrict__ hA){
  int tid = blockIdx.x*256 + threadIdx.x;          // 131,072
  hA[tid] = f2bf(0.f);                             // h0 = 0
}

// =================================================================
// LDS fragment layout helpers (identical to R8).
// lds_h: 16 rows x 1024 cols, unit kk (0..31): lane's 8 elems =
//   h[lane&15][kk*32 + (lane>>4)*8 + e]  at  lds_h[kk*512 + lane*8].
// =================================================================
__device__ __forceinline__ v8bf afrag(const bf16* lds_h, int kk, int lane){
  return ldv(lds_h + (size_t)kk*512 + (size_t)lane*8);
}
__device__ __forceinline__ float hp16(const bf16* lds_h, int rl, int colh){
  int kk = colh >> 5, q = (colh >> 3) & 3, e = colh & 7;
  return bf2f(lds_h[(size_t)kk*512 + (size_t)(q*16 + rl)*8 + e]);
}

#define MFMA(a,b,c) __builtin_amdgcn_mfma_f32_16x16x32_bf16((a),(b),(c),0,0,0)

// lds2 tile: 16x16 f32 at stride 17 (pad), tile stride 272
#define T_W(w, row, col)  lds2[(w)*272 + (row)*17 + (col)]

// stage 16 rows x 1024 cols of h (row stride 1024) -> fragment LDS, plain loads
__device__ __forceinline__ void stage16(const bf16* __restrict__ src_rg, bf16* lds_h,
                                        int wave, int lane, int l15, int quad){
  const bf16* g0 = src_rg + (size_t)l15*1024 + wave*64 + quad*8;
  v4u r0 = *(const v4u*)g0;
  v4u r1 = *(const v4u*)(g0 + 32);
  bf16* d = lds_h + (size_t)(wave*2)*512 + (size_t)lane*8;
  *(v4u*)(d)       = r0;
  *(v4u*)(d + 512) = r1;
}

// =================================================================
// L0 kernel (one timestep): fused IC(t-1) + hB = GRU0(comp(t-1), hA).
// Grid 128 x 1024: cseg = bid&15 (64 cols, cseg&7 = XCD), g = bid>>4 (16 rows).
// =================================================================
__global__ __launch_bounds__(1024) void gru_l0(
  const int t,
  const float* __restrict__ x, const float* __restrict__ masks,
  const float* __restrict__ bih0, const float* __restrict__ bhh0,
  const float* __restrict__ bp,
  const bf16* __restrict__ packL0h, const bf16* __restrict__ packL0x,
  const bf16* __restrict__ packImp,
  const bf16* __restrict__ hA, bf16* __restrict__ hB,
  float* __restrict__ out)
{
  const int tid  = threadIdx.x;
  const int lane = tid & 63;
  const int wave = tid >> 6;
  const int l15  = lane & 15;
  const int quad = lane >> 4;
  const int bid  = blockIdx.x;
  const int cseg = bid & 15;
  const int g    = bid >> 4;
  const int rB   = g * 16;

  __shared__ bf16 lds_h[16384];        // 32 KB staged h slice
  __shared__ bf16 lds_c[2048];         // 4 KB staged comp slice
  __shared__ float lds2[24*272];       // ~25.5 KB partial tiles (padded)

  stage16(hA + (size_t)rB*1024, lds_h, wave, lane, l15, quad);
  __syncthreads();

  // ---- fused IC: build comp(t-1) slice into lds_c; write out for t>=1 ----
  if (t == 0){
    // comp(-1) = x[:, 0, :]; wave = row rl, lane -> d, d+64
    const int rl = wave;
    #pragma unroll
    for (int half=0; half<2; ++half){
      const int d = lane + half*64;
      float v = x[(size_t)(rB+rl)*16384 + d];
      lds_c[(size_t)(d>>5)*512 + (size_t)(((d>>3)&3)*16 + rl)*8 + (d&7)] = f2bf(v);
    }
  } else {
    // imp(t-1)[16,128] = lds_h @ Wp^T + bp, redundant per block.
    // wave w: d-tile jt=w>>1, K-half kh=w&1 (16 kk each)
    const int jt = wave >> 1, kh = wave & 1;
    v4f acc = {0.f,0.f,0.f,0.f};
    const bf16* wp = packImp + ((size_t)(jt*32 + kh*16))*512 + lane*8;
    #pragma unroll
    for (int i=0;i<16;++i){
      acc = MFMA(afrag(lds_h, kh*16+i, lane), ldv(wp + (size_t)i*512), acc);
    }
    #pragma unroll
    for (int r=0;r<4;r++) T_W(wave, quad*4+r, l15) = acc[r];
    __syncthreads();
    // epilogue: wave = row rl, lane -> d, d+64
    const int rl = wave, tm = t - 1;
    const float m = masks[(size_t)(rB+rl)*128 + tm];
    #pragma unroll
    for (int half=0; half<2; ++half){
      const int d = lane + half*64;
      const int djt = d >> 4, c = d & 15;
      float imp = T_W(djt*2, rl, c) + T_W(djt*2+1, rl, c) + bp[d];
      float xv  = x[((size_t)(rB+rl)*128 + tm)*128 + d];
      float cv  = m*xv + (1.f - m)*imp;
      lds_c[(size_t)(d>>5)*512 + (size_t)(((d>>3)&3)*16 + rl)*8 + (d&7)] = f2bf(cv);
      if ((d >> 3) == cseg){
        size_t o = ((size_t)(rB+rl)*127 + tm)*128 + d;
        out[131072 + o]  = cv;    // completed
        out[2211840 + o] = imp;   // imputed
      }
    }
  }
  __syncthreads();

  // ---- main L0 matmuls ----
  if (wave < 12){
    // h-part: wave = gate*4 + jt, full K=1024 (2 accumulators)
    const int gg = wave >> 2, jt = wave & 3;
    const int j = cseg*4 + jt;
    v4f a0 = {0.f,0.f,0.f,0.f}, a1 = {0.f,0.f,0.f,0.f};
    const bf16* wp = packL0h + ((size_t)((gg*64 + j)*32))*512 + lane*8;
    #pragma unroll
    for (int i=0;i<32;i+=2){
      a0 = MFMA(afrag(lds_h, i,   lane), ldv(wp + (size_t)i*512),     a0);
      a1 = MFMA(afrag(lds_h, i+1, lane), ldv(wp + (size_t)(i+1)*512), a1);
    }
    const v4f a = a0 + a1;
    #pragma unroll
    for (int r=0;r<4;r++) T_W(wave, quad*4+r, l15) = a[r];
  } else {
    // x-part: wave 12+jt handles gates 0..2, K=128
    const int jt = wave - 12;
    const int j = cseg*4 + jt;
    #pragma unroll
    for (int gg=0; gg<3; ++gg){
      v4f a = {0.f,0.f,0.f,0.f};
      const bf16* wp = packL0x + ((size_t)((gg*64 + j)*4))*512 + lane*8;
      #pragma unroll
      for (int i=0;i<4;++i){
        a = MFMA(ldv(lds_c + (size_t)i*512 + lane*8), ldv(wp + (size_t)i*512), a);
      }
      const int slot = 12 + gg*4 + jt;
      #pragma unroll
      for (int r=0;r<4;r++) T_W(slot, quad*4+r, l15) = a[r];
    }
  }
  __syncthreads();
  {
    const int rl = wave, cb = lane;
    const int jt = cb >> 4, c = cb & 15;
    const int col = cseg*64 + cb;
    float ghr = T_W(0*4+jt, rl, c);
    float ghz = T_W(1*4+jt, rl, c);
    float ghn = T_W(2*4+jt, rl, c);
    float gir = T_W(12+0*4+jt, rl, c);
    float giz = T_W(12+1*4+jt, rl, c);
    float gin = T_W(12+2*4+jt, rl, c);
    float rgg = sigm(gir + bih0[col]      + ghr + bhh0[col]);
    float zg  = sigm(giz + bih0[1024+col] + ghz + bhh0[1024+col]);
    float nv  = tanh_(gin + bih0[2048+col] + rgg*(ghn + bhh0[2048+col]));
    float hp  = hp16(lds_h, rl, col);
    hB[(size_t)(rB+rl)*1024 + col] = f2bf((1.f - zg)*nv + zg*hp);
  }
}

// =================================================================
// Upper-layer kernel: dst = GRU_lay(src, src)  (input == hidden).
// lay=0: hB->hC, lay=1: hC->hA (+ h_final out at t==127).
// =================================================================
__global__ __launch_bounds__(1024) void gru_up(
  const int lay, const int t,
  const float* __restrict__ bihR, const float* __restrict__ bhhR,
  const bf16* __restrict__ packU,
  const bf16* __restrict__ src, bf16* __restrict__ dst,
  float* __restrict__ out)
{
  const int tid  = threadIdx.x;
  const int lane = tid & 63;
  const int wave = tid >> 6;
  const int l15  = lane & 15;
  const int quad = lane >> 4;
  const int bid  = blockIdx.x;
  const int cseg = bid & 15;
  const int g    = bid >> 4;
  const int rB   = g * 16;
  const bf16* packL = packU + (size_t)lay*4194304;
  const float* bi = bihR + lay*3072;
  const float* bh = bhhR + lay*3072;
  float* out_h = (lay == 1 && t == 127) ? out : nullptr;

  __shared__ bf16 lds_h[16384];
  __shared__ float lds2[16*272];

  stage16(src + (size_t)rB*1024, lds_h, wave, lane, l15, quad);
  __syncthreads();
  {
    // wave = jt*4 + s; full K=1024 (2 accumulators)
    const int s = wave & 3, jt = wave >> 2;
    const int j = cseg*4 + jt;
    v4f a0 = {0.f,0.f,0.f,0.f}, a1 = {0.f,0.f,0.f,0.f};
    const bf16* wp = packL + ((size_t)((s*64 + j)*32))*512 + lane*8;
    #pragma unroll
    for (int i=0;i<32;i+=2){
      a0 = MFMA(afrag(lds_h, i,   lane), ldv(wp + (size_t)i*512),     a0);
      a1 = MFMA(afrag(lds_h, i+1, lane), ldv(wp + (size_t)(i+1)*512), a1);
    }
    const v4f a = a0 + a1;
    #pragma unroll
    for (int r=0;r<4;r++) T_W(wave, quad*4+r, l15) = a[r];
  }
  __syncthreads();
  {
    const int rl = wave, cb = lane;
    const int jt = cb >> 4, c = cb & 15;
    const int col = cseg*64 + cb;
    float pr  = T_W(jt*4+0, rl, c);
    float pz  = T_W(jt*4+1, rl, c);
    float pin = T_W(jt*4+2, rl, c);
    float phn = T_W(jt*4+3, rl, c);
    float rgg = sigm(pr + bi[col] + bh[col]);
    float zg  = sigm(pz + bi[1024+col] + bh[1024+col]);
    float nv  = tanh_(pin + bi[2048+col] + rgg*(phn + bh[2048+col]));
    float hp  = hp16(lds_h, rl, col);
    float hv  = (1.f - zg)*nv + zg*hp;
    dst[(size_t)(rB+rl)*1024 + col] = f2bf(hv);
    if (out_h) out_h[(size_t)(rB+rl)*1024 + col] = hv;
  }
}

// ---------------- host ----------------
extern "C" void kernel_launch(void* const* d_in, const int* in_sizes, int n_in,
                              void* d_out, int out_size, void* d_ws, size_t ws_size,
                              hipStream_t stream)
{
  (void)in_sizes; (void)n_in; (void)out_size; (void)ws_size;
  const float* x     = (const float*)d_in[0];
  const float* masks = (const float*)d_in[1];
  const float* Wih0  = (const float*)d_in[2];
  const float* Whh0  = (const float*)d_in[3];
  const float* bih0  = (const float*)d_in[4];
  const float* bhh0  = (const float*)d_in[5];
  const float* WihR  = (const float*)d_in[6];
  const float* WhhR  = (const float*)d_in[7];
  const float* bihR  = (const float*)d_in[8];
  const float* bhhR  = (const float*)d_in[9];
  const float* Wp    = (const float*)d_in[10];
  const float* bp    = (const float*)d_in[11];
  float* out = (float*)d_out;

  // ws: pad 4096B | hA hB hC (bf16 131072 ea) | packed weights
  bf16* hA      = (bf16*)((char*)d_ws + 4096);
  bf16* hB      = hA + 131072;
  bf16* hC      = hB + 131072;
  bf16* packU   = hC + 131072;         // 8,388,608 elems
  bf16* packL0h = packU + 8388608;     // 3,145,728
  bf16* packL0x = packL0h + 3145728;   // 393,216
  bf16* packImp = packL0x + 393216;    // 131,072

  hipLaunchKernelGGL(init_pk,      dim3(512),  dim3(256), 0, stream, hA);
  hipLaunchKernelGGL(pack_upper_k, dim3(4096), dim3(256), 0, stream, WihR, WhhR, packU);
  hipLaunchKernelGGL(pack_l0h_k,   dim3(1536), dim3(256), 0, stream, Whh0, packL0h);
  hipLaunchKernelGGL(pack_l0x_k,   dim3(192),  dim3(256), 0, stream, Wih0, packL0x);
  hipLaunchKernelGGL(pack_imp_k,   dim3(64),   dim3(256), 0, stream, Wp, packImp);

  for (int t = 0; t < 128; ++t){
    hipLaunchKernelGGL(gru_l0, dim3(128), dim3(1024), 0, stream,
        t, x, masks, bih0, bhh0, bp, packL0h, packL0x, packImp, hA, hB, out);
    hipLaunchKernelGGL(gru_up, dim3(128), dim3(1024), 0, stream,
        0, t, bihR, bhhR, packU, hB, hC, out);
    hipLaunchKernelGGL(gru_up, dim3(128), dim3(1024), 0, stream,
        1, t, bihR, bhhR, packU, hC, hA, out);
  }
}

// Round 9
// 2982.649 us; speedup vs baseline: 2.1350x; 1.2131x over previous
//
#include <hip/hip_runtime.h>
#include <hip/hip_bf16.h>

// GRU-imputation scan (B=128,T=128,D=128,H=1024,L=3), f32 in/out.
// Round 11: widen the pipeline. R10's 384-kernel chain used 128 blocks x 1024
// threads (half the CUs; 512 KB weight stream per block ~3.3us). Re-split to
// 256 blocks x 512 threads: all 256 CUs busy, 256 KB weights per block
// (~1.7us stream). cseg = bid&31 (32 cols per block), g = bid>>5 (16 rows);
// cseg%8 == bid%8 == XCD preserves weight L2 affinity. Compute bodies are
// the validated R8/R10 fragment layouts remapped to 8 waves.

typedef __hip_bfloat16 bf16;
typedef unsigned int u32;
typedef unsigned short u16;
typedef __attribute__((ext_vector_type(8))) short v8bf;   // 8 x bf16 (16B)
typedef __attribute__((ext_vector_type(4))) float v4f;    // MFMA C/D
typedef __attribute__((ext_vector_type(4))) u32 v4u;

__device__ __forceinline__ float bf2f(bf16 v){ return __bfloat162float(v); }
__device__ __forceinline__ bf16 f2bf(float v){ return __float2bfloat16(v); }
__device__ __forceinline__ float sigm(float x){ return 1.f/(1.f + __expf(-x)); }
__device__ __forceinline__ float tanh_(float x){
  float a = fminf(fmaxf(x, -15.f), 15.f);
  float t = __expf(2.f*a);
  return (t-1.f)/(t+1.f);
}
__device__ __forceinline__ v8bf ldv(const bf16* p){ return *reinterpret_cast<const v8bf*>(p); }

// =================================================================
// Packing kernels (unchanged; validated).
// Fragment unit = 64 lanes x 8 bf16; lane's 8 elems =
//   W[row(j,lane&15)][kk*32 + ((lane>>4)&3)*8 + e]
// =================================================================
__global__ void pack_upper_k(const float* __restrict__ Wih, const float* __restrict__ Whh,
                             bf16* __restrict__ dst){
  int tid = blockIdx.x*256 + threadIdx.x;          // 1,048,576
  int lane = tid & 63;
  int u    = tid >> 6;
  int kk   = u & 31;
  int j    = (u >> 5) & 63;
  int s    = (u >> 11) & 3;
  int l    = u >> 13;
  int n    = j*16 + (lane & 15);
  int k    = kk*32 + ((lane>>4)&3)*8;
  int row  = (s==0) ? n : (s==1 ? 1024+n : 2048+n);
  size_t src = ((size_t)l*3072 + row)*1024 + k;
  size_t o = (size_t)tid*8;
  #pragma unroll
  for (int e=0;e<8;e++){
    float v;
    if (s < 2)      v = Wih[src+e] + Whh[src+e];
    else if (s==2)  v = Wih[src+e];
    else            v = Whh[src+e];
    dst[o+e] = f2bf(v);
  }
}
__global__ void pack_l0h_k(const float* __restrict__ Whh0, bf16* __restrict__ dst){
  int tid = blockIdx.x*256 + threadIdx.x;          // 393,216
  int lane = tid & 63;
  int u  = tid >> 6;
  int kk = u & 31;
  int j  = (u >> 5) & 63;
  int g  = u >> 11;
  int row = g*1024 + j*16 + (lane&15);
  int k   = kk*32 + ((lane>>4)&3)*8;
  size_t src = (size_t)row*1024 + k;
  size_t o = (size_t)tid*8;
  #pragma unroll
  for (int e=0;e<8;e++) dst[o+e] = f2bf(Whh0[src+e]);
}
__global__ void pack_l0x_k(const float* __restrict__ Wih0, bf16* __restrict__ dst){
  int tid = blockIdx.x*256 + threadIdx.x;          // 49,152
  int lane = tid & 63;
  int u  = tid >> 6;
  int kk = u & 3;
  int j  = (u >> 2) & 63;
  int g  = u >> 8;
  int row = g*1024 + j*16 + (lane&15);
  int k   = kk*32 + ((lane>>4)&3)*8;
  size_t src = (size_t)row*128 + k;
  size_t o = (size_t)tid*8;
  #pragma unroll
  for (int e=0;e<8;e++) dst[o+e] = f2bf(Wih0[src+e]);
}
__global__ void pack_imp_k(const float* __restrict__ Wp, bf16* __restrict__ dst){
  int tid = blockIdx.x*256 + threadIdx.x;          // 16,384
  int lane = tid & 63;
  int u  = tid >> 6;
  int kk = u & 31;
  int jj = u >> 5;
  int row = jj*16 + (lane&15);
  int k   = kk*32 + ((lane>>4)&3)*8;
  size_t src = (size_t)row*1024 + k;
  size_t o = (size_t)tid*8;
  #pragma unroll
  for (int e=0;e<8;e++) dst[o+e] = f2bf(Wp[src+e]);
}
__global__ void init_pk(bf16* __restrict__ hA){
  int tid = blockIdx.x*256 + threadIdx.x;          // 131,072
  hA[tid] = f2bf(0.f);                             // h0 = 0
}

// =================================================================
// LDS fragment layout (validated): lds_h = 16 rows x 1024 cols,
// unit kk (0..31): lane's 8 elems = h[lane&15][kk*32 + (lane>>4)*8 + e]
// at lds_h[kk*512 + lane*8].
// =================================================================
__device__ __forceinline__ v8bf afrag(const bf16* lds_h, int kk, int lane){
  return ldv(lds_h + (size_t)kk*512 + (size_t)lane*8);
}
__device__ __forceinline__ float hp16(const bf16* lds_h, int rl, int colh){
  int kk = colh >> 5, q = (colh >> 3) & 3, e = colh & 7;
  return bf2f(lds_h[(size_t)kk*512 + (size_t)(q*16 + rl)*8 + e]);
}

#define MFMA(a,b,c) __builtin_amdgcn_mfma_f32_16x16x32_bf16((a),(b),(c),0,0,0)

// lds2 tile: 16x16 f32 at stride 17 (pad), tile stride 272
#define T_W(w, row, col)  lds2[(w)*272 + (row)*17 + (col)]

// stage 16 rows x 1024 cols of h -> fragment LDS; 8 waves, wave w stages
// kk = 4w..4w+3 (plain cached loads).
__device__ __forceinline__ void stage16_8(const bf16* __restrict__ src_rg, bf16* lds_h,
                                          int wave, int lane, int l15, int quad){
  const bf16* g0 = src_rg + (size_t)l15*1024 + wave*128 + quad*8;
  v4u r0 = *(const v4u*)(g0);
  v4u r1 = *(const v4u*)(g0 + 32);
  v4u r2 = *(const v4u*)(g0 + 64);
  v4u r3 = *(const v4u*)(g0 + 96);
  bf16* d = lds_h + (size_t)(wave*4)*512 + (size_t)lane*8;
  *(v4u*)(d)        = r0;
  *(v4u*)(d + 512)  = r1;
  *(v4u*)(d + 1024) = r2;
  *(v4u*)(d + 1536) = r3;
}

// =================================================================
// L0 kernel (one timestep): fused IC(t-1) + hB = GRU0(comp(t-1), hA).
// Grid 256 x 512: cseg = bid&31 (32 cols, cseg%8 = XCD), g = bid>>5 (16 rows).
// =================================================================
__global__ __launch_bounds__(512) void gru_l0(
  const int t,
  const float* __restrict__ x, const float* __restrict__ masks,
  const float* __restrict__ bih0, const float* __restrict__ bhh0,
  const float* __restrict__ bp,
  const bf16* __restrict__ packL0h, const bf16* __restrict__ packL0x,
  const bf16* __restrict__ packImp,
  const bf16* __restrict__ hA, bf16* __restrict__ hB,
  float* __restrict__ out)
{
  const int tid  = threadIdx.x;
  const int lane = tid & 63;
  const int wave = tid >> 6;           // 0..7
  const int l15  = lane & 15;
  const int quad = lane >> 4;
  const int bid  = blockIdx.x;
  const int cseg = bid & 31;
  const int g    = bid >> 5;
  const int rB   = g * 16;

  __shared__ bf16 lds_h[16384];        // 32 KB staged h slice
  __shared__ bf16 lds_c[2048];         // 4 KB staged comp slice
  __shared__ float lds2[12*272];       // ~12.8 KB partial tiles (padded)

  stage16_8(hA + (size_t)rB*1024, lds_h, wave, lane, l15, quad);
  __syncthreads();

  // ---- fused IC: build comp(t-1) slice into lds_c; write out for t>=1 ----
  if (t == 0){
    // comp(-1) = x[:, 0, :]; thread: rl = tid>>5, cb = tid&31 -> d = cb*4..+3
    const int rl = tid >> 5, cb = tid & 31;
    #pragma unroll
    for (int k=0;k<4;++k){
      const int d = cb*4 + k;
      float v = x[(size_t)(rB+rl)*16384 + d];
      lds_c[(size_t)(d>>5)*512 + (size_t)(((d>>3)&3)*16 + rl)*8 + (d&7)] = f2bf(v);
    }
  } else {
    // imp(t-1)[16,128] = lds_h @ Wp^T + bp, redundant per block.
    // wave = d-tile jt (0..7), full K: 32 MFMAs (2 accumulators).
    {
      const int jt = wave;
      v4f a0 = {0.f,0.f,0.f,0.f}, a1 = {0.f,0.f,0.f,0.f};
      const bf16* wp = packImp + ((size_t)(jt*32))*512 + lane*8;
      #pragma unroll
      for (int i=0;i<32;i+=2){
        a0 = MFMA(afrag(lds_h, i,   lane), ldv(wp + (size_t)i*512),     a0);
        a1 = MFMA(afrag(lds_h, i+1, lane), ldv(wp + (size_t)(i+1)*512), a1);
      }
      const v4f a = a0 + a1;
      #pragma unroll
      for (int r=0;r<4;r++) T_W(jt, quad*4+r, l15) = a[r];
    }
    __syncthreads();
    // epilogue: thread rl = tid>>5, cb = tid&31 -> d = cb*4..+3
    const int rl = tid >> 5, cb = tid & 31, tm = t - 1;
    const float m = masks[(size_t)(rB+rl)*128 + tm];
    const bool wr = (cb == cseg);                 // unique writer per 4 cols
    #pragma unroll
    for (int k=0;k<4;++k){
      const int d = cb*4 + k;
      const int djt = d >> 4, c = d & 15;
      float imp = T_W(djt, rl, c) + bp[d];
      float xv  = x[((size_t)(rB+rl)*128 + tm)*128 + d];
      float cv  = m*xv + (1.f - m)*imp;
      lds_c[(size_t)(d>>5)*512 + (size_t)(((d>>3)&3)*16 + rl)*8 + (d&7)] = f2bf(cv);
      if (wr){
        size_t o = ((size_t)(rB+rl)*127 + tm)*128 + d;
        out[131072 + o]  = cv;    // completed
        out[2211840 + o] = imp;   // imputed
      }
    }
  }
  __syncthreads();

  // ---- main L0 matmuls ----
  if (wave < 6){
    // h-part: wave = gate*2 + jt, full K=1024 (2 accumulators)
    const int gg = wave >> 1, jt = wave & 1;
    const int j = cseg*2 + jt;
    v4f a0 = {0.f,0.f,0.f,0.f}, a1 = {0.f,0.f,0.f,0.f};
    const bf16* wp = packL0h + ((size_t)((gg*64 + j)*32))*512 + lane*8;
    #pragma unroll
    for (int i=0;i<32;i+=2){
      a0 = MFMA(afrag(lds_h, i,   lane), ldv(wp + (size_t)i*512),     a0);
      a1 = MFMA(afrag(lds_h, i+1, lane), ldv(wp + (size_t)(i+1)*512), a1);
    }
    const v4f a = a0 + a1;
    #pragma unroll
    for (int r=0;r<4;r++) T_W(wave, quad*4+r, l15) = a[r];
  } else {
    // x-part: wave 6+jt handles gates 0..2, K=128 (4 MFMAs each)
    const int jt = wave - 6;
    const int j = cseg*2 + jt;
    #pragma unroll
    for (int gg=0; gg<3; ++gg){
      v4f a = {0.f,0.f,0.f,0.f};
      const bf16* wp = packL0x + ((size_t)((gg*64 + j)*4))*512 + lane*8;
      #pragma unroll
      for (int i=0;i<4;++i){
        a = MFMA(ldv(lds_c + (size_t)i*512 + lane*8), ldv(wp + (size_t)i*512), a);
      }
      const int slot = 6 + gg*2 + jt;
      #pragma unroll
      for (int r=0;r<4;r++) T_W(slot, quad*4+r, l15) = a[r];
    }
  }
  __syncthreads();
  {
    const int rl = tid >> 5, cb = tid & 31;
    const int jt = cb >> 4, c = cb & 15;
    const int col = cseg*32 + cb;
    float ghr = T_W(0*2+jt, rl, c);
    float ghz = T_W(1*2+jt, rl, c);
    float ghn = T_W(2*2+jt, rl, c);
    float gir = T_W(6+0*2+jt, rl, c);
    float giz = T_W(6+1*2+jt, rl, c);
    float gin = T_W(6+2*2+jt, rl, c);
    float rgg = sigm(gir + bih0[col]      + ghr + bhh0[col]);
    float zg  = sigm(giz + bih0[1024+col] + ghz + bhh0[1024+col]);
    float nv  = tanh_(gin + bih0[2048+col] + rgg*(ghn + bhh0[2048+col]));
    float hp  = hp16(lds_h, rl, col);
    hB[(size_t)(rB+rl)*1024 + col] = f2bf((1.f - zg)*nv + zg*hp);
  }
}

// =================================================================
// Upper-layer kernel: dst = GRU_lay(src, src)  (input == hidden).
// lay=0: hB->hC, lay=1: hC->hA (+ h_final out at t==127).
// Grid 256 x 512: wave = s*2 + jt (4 gates x 2 j-tiles), full K=1024.
// =================================================================
__global__ __launch_bounds__(512) void gru_up(
  const int lay, const int t,
  const float* __restrict__ bihR, const float* __restrict__ bhhR,
  const bf16* __restrict__ packU,
  const bf16* __restrict__ src, bf16* __restrict__ dst,
  float* __restrict__ out)
{
  const int tid  = threadIdx.x;
  const int lane = tid & 63;
  const int wave = tid >> 6;           // 0..7
  const int l15  = lane & 15;
  const int quad = lane >> 4;
  const int bid  = blockIdx.x;
  const int cseg = bid & 31;
  const int g    = bid >> 5;
  const int rB   = g * 16;
  const bf16* packL = packU + (size_t)lay*4194304;
  const float* bi = bihR + lay*3072;
  const float* bh = bhhR + lay*3072;
  float* out_h = (lay == 1 && t == 127) ? out : nullptr;

  __shared__ bf16 lds_h[16384];
  __shared__ float lds2[8*272];

  stage16_8(src + (size_t)rB*1024, lds_h, wave, lane, l15, quad);
  __syncthreads();
  {
    // wave = s*2 + jt; full K=1024 (2 accumulators)
    const int s = wave >> 1, jt = wave & 1;
    const int j = cseg*2 + jt;
    v4f a0 = {0.f,0.f,0.f,0.f}, a1 = {0.f,0.f,0.f,0.f};
    const bf16* wp = packL + ((size_t)((s*64 + j)*32))*512 + lane*8;
    #pragma unroll
    for (int i=0;i<32;i+=2){
      a0 = MFMA(afrag(lds_h, i,   lane), ldv(wp + (size_t)i*512),     a0);
      a1 = MFMA(afrag(lds_h, i+1, lane), ldv(wp + (size_t)(i+1)*512), a1);
    }
    const v4f a = a0 + a1;
    #pragma unroll
    for (int r=0;r<4;r++) T_W(wave, quad*4+r, l15) = a[r];
  }
  __syncthreads();
  {
    const int rl = tid >> 5, cb = tid & 31;
    const int jt = cb >> 4, c = cb & 15;
    const int col = cseg*32 + cb;
    float pr  = T_W(0*2+jt, rl, c);
    float pz  = T_W(1*2+jt, rl, c);
    float pin = T_W(2*2+jt, rl, c);
    float phn = T_W(3*2+jt, rl, c);
    float rgg = sigm(pr + bi[col] + bh[col]);
    float zg  = sigm(pz + bi[1024+col] + bh[1024+col]);
    float nv  = tanh_(pin + bi[2048+col] + rgg*(phn + bh[2048+col]));
    float hp  = hp16(lds_h, rl, col);
    float hv  = (1.f - zg)*nv + zg*hp;
    dst[(size_t)(rB+rl)*1024 + col] = f2bf(hv);
    if (out_h) out_h[(size_t)(rB+rl)*1024 + col] = hv;
  }
}

// ---------------- host ----------------
extern "C" void kernel_launch(void* const* d_in, const int* in_sizes, int n_in,
                              void* d_out, int out_size, void* d_ws, size_t ws_size,
                              hipStream_t stream)
{
  (void)in_sizes; (void)n_in; (void)out_size; (void)ws_size;
  const float* x     = (const float*)d_in[0];
  const float* masks = (const float*)d_in[1];
  const float* Wih0  = (const float*)d_in[2];
  const float* Whh0  = (const float*)d_in[3];
  const float* bih0  = (const float*)d_in[4];
  const float* bhh0  = (const float*)d_in[5];
  const float* WihR  = (const float*)d_in[6];
  const float* WhhR  = (const float*)d_in[7];
  const float* bihR  = (const float*)d_in[8];
  const float* bhhR  = (const float*)d_in[9];
  const float* Wp    = (const float*)d_in[10];
  const float* bp    = (const float*)d_in[11];
  float* out = (float*)d_out;

  // ws: pad 4096B | hA hB hC (bf16 131072 ea) | packed weights
  bf16* hA      = (bf16*)((char*)d_ws + 4096);
  bf16* hB      = hA + 131072;
  bf16* hC      = hB + 131072;
  bf16* packU   = hC + 131072;         // 8,388,608 elems
  bf16* packL0h = packU + 8388608;     // 3,145,728
  bf16* packL0x = packL0h + 3145728;   // 393,216
  bf16* packImp = packL0x + 393216;    // 131,072

  hipLaunchKernelGGL(init_pk,      dim3(512),  dim3(256), 0, stream, hA);
  hipLaunchKernelGGL(pack_upper_k, dim3(4096), dim3(256), 0, stream, WihR, WhhR, packU);
  hipLaunchKernelGGL(pack_l0h_k,   dim3(1536), dim3(256), 0, stream, Whh0, packL0h);
  hipLaunchKernelGGL(pack_l0x_k,   dim3(192),  dim3(256), 0, stream, Wih0, packL0x);
  hipLaunchKernelGGL(pack_imp_k,   dim3(64),   dim3(256), 0, stream, Wp, packImp);

  for (int t = 0; t < 128; ++t){
    hipLaunchKernelGGL(gru_l0, dim3(256), dim3(512), 0, stream,
        t, x, masks, bih0, bhh0, bp, packL0h, packL0x, packImp, hA, hB, out);
    hipLaunchKernelGGL(gru_up, dim3(256), dim3(512), 0, stream,
        0, t, bihR, bhhR, packU, hB, hC, out);
    hipLaunchKernelGGL(gru_up, dim3(256), dim3(512), 0, stream,
        1, t, bihR, bhhR, packU, hC, hA, out);
  }
}